// Round 18
// baseline (138.645 us; speedup 1.0000x reference)
//
#include <hip/hip_runtime.h>
#include <hip/hip_fp16.h>

#define F_IN 128
#define H1   16
#define C2   8
#define BSHIFT 7
#define BNODES 128            // nodes per bucket
#define MAXBUCK 1024          // LDS array bound (runtime nbuck=782)
#define NBLK 256              // binning windows (== runs per bucket)
#define BIN_TB 1024           // binScatter2 threads
#define SORT_TB 512           // sortCSR threads: 2 per run
#define CAP  6144             // sortCSR LDS record staging (avg bucket = 4096)
#define CHUNK_CAP 12800       // binScatter2 per-block edge capacity (chunk = 12500)

// ---------- merged binning: 1-atomic-per-edge rank fusion + positioned writes ----------
__global__ __launch_bounds__(BIN_TB) void binScatter2_kernel(
        const int* __restrict__ ei, int E, int chunk, int nbuck,
        int* __restrict__ bbcScan, int* __restrict__ stage) {
    __shared__ int h[MAXBUCK];
    __shared__ int sc[512];
    __shared__ unsigned short rnk[CHUNK_CAP];
    int t = threadIdx.x;
    int blk = blockIdx.x;
    int base = blk * chunk;
    int csize = max(0, min(chunk, E - base));
    int blkBase = base;

    for (int i = t; i < MAXBUCK; i += BIN_TB) h[i] = 0;
    __syncthreads();

    const int* colp = ei + E + base;
    const int* rowp = ei + base;
    bool al4 = ((E & 3) == 0) && ((base & 3) == 0) && ((csize & 3) == 0);
    bool fit = (csize <= CHUNK_CAP);

    // pass 1: histogram; atomicAdd doubles as rank assignment
    if (al4) {
        const int4* cv = reinterpret_cast<const int4*>(colp);
        int nv = csize >> 2;
        if (fit) {
            for (int i = t; i < nv; i += BIN_TB) {
                int4 c4 = cv[i];
                rnk[4 * i + 0] = (unsigned short)atomicAdd(&h[c4.x >> BSHIFT], 1);
                rnk[4 * i + 1] = (unsigned short)atomicAdd(&h[c4.y >> BSHIFT], 1);
                rnk[4 * i + 2] = (unsigned short)atomicAdd(&h[c4.z >> BSHIFT], 1);
                rnk[4 * i + 3] = (unsigned short)atomicAdd(&h[c4.w >> BSHIFT], 1);
            }
        } else {
            for (int i = t; i < nv; i += BIN_TB) {
                int4 c4 = cv[i];
                atomicAdd(&h[c4.x >> BSHIFT], 1);
                atomicAdd(&h[c4.y >> BSHIFT], 1);
                atomicAdd(&h[c4.z >> BSHIFT], 1);
                atomicAdd(&h[c4.w >> BSHIFT], 1);
            }
        }
    } else {
        if (fit) {
            for (int i = t; i < csize; i += BIN_TB)
                rnk[i] = (unsigned short)atomicAdd(&h[colp[i] >> BSHIFT], 1);
        } else {
            for (int i = t; i < csize; i += BIN_TB) atomicAdd(&h[colp[i] >> BSHIFT], 1);
        }
    }
    __syncthreads();

    // in-block exclusive scan of h[0..1024); threads t<512 own entries 2t, 2t+1
    int e0 = 0, e1 = 0, psum = 0;
    if (t < 512) {
        e0 = h[2 * t]; e1 = h[2 * t + 1];
        psum = e0 + e1;
        sc[t] = psum;
    }
    __syncthreads();
    for (int off = 1; off < 512; off <<= 1) {
        int tmp = (t < 512 && t >= off) ? sc[t - off] : 0;
        __syncthreads();
        if (t < 512) sc[t] += tmp;
        __syncthreads();
    }
    if (t < 512) {
        int excl = sc[t] - psum;
        h[2 * t] = blkBase + excl;          // run base (fixed in fit path)
        h[2 * t + 1] = blkBase + excl + e0;
    }
    __syncthreads();

    // publish run starts for sortCSR
    for (int b = t; b < nbuck; b += BIN_TB)
        bbcScan[blk * nbuck + b] = h[b];
    __syncthreads();

    // pass 2: positioned writes (edges re-read from block-private L2-hot chunk)
    if (al4) {
        const int4* cv = reinterpret_cast<const int4*>(colp);
        const int4* rv = reinterpret_cast<const int4*>(rowp);
        int nv = csize >> 2;
        if (fit) {
            for (int i = t; i < nv; i += BIN_TB) {
                int4 c4 = cv[i];
                int4 r4 = rv[i];
                stage[h[c4.x >> BSHIFT] + (int)rnk[4 * i + 0]] = (r4.x << BSHIFT) | (c4.x & (BNODES - 1));
                stage[h[c4.y >> BSHIFT] + (int)rnk[4 * i + 1]] = (r4.y << BSHIFT) | (c4.y & (BNODES - 1));
                stage[h[c4.z >> BSHIFT] + (int)rnk[4 * i + 2]] = (r4.z << BSHIFT) | (c4.z & (BNODES - 1));
                stage[h[c4.w >> BSHIFT] + (int)rnk[4 * i + 3]] = (r4.w << BSHIFT) | (c4.w & (BNODES - 1));
            }
        } else {
            for (int i = t; i < nv; i += BIN_TB) {
                int4 c4 = cv[i];
                int4 r4 = rv[i];
                int p0 = atomicAdd(&h[c4.x >> BSHIFT], 1);
                stage[p0] = (r4.x << BSHIFT) | (c4.x & (BNODES - 1));
                int p1 = atomicAdd(&h[c4.y >> BSHIFT], 1);
                stage[p1] = (r4.y << BSHIFT) | (c4.y & (BNODES - 1));
                int p2 = atomicAdd(&h[c4.z >> BSHIFT], 1);
                stage[p2] = (r4.z << BSHIFT) | (c4.z & (BNODES - 1));
                int p3 = atomicAdd(&h[c4.w >> BSHIFT], 1);
                stage[p3] = (r4.w << BSHIFT) | (c4.w & (BNODES - 1));
            }
        }
    } else {
        if (fit) {
            for (int i = t; i < csize; i += BIN_TB) {
                int r = rowp[i];
                int c = colp[i];
                stage[h[c >> BSHIFT] + (int)rnk[i]] = (r << BSHIFT) | (c & (BNODES - 1));
            }
        } else {
            for (int i = t; i < csize; i += BIN_TB) {
                int r = rowp[i];
                int c = colp[i];
                int p = atomicAdd(&h[c >> BSHIFT], 1);
                stage[p] = (r << BSHIFT) | (c & (BNODES - 1));
            }
        }
    }
}

// ---------- within-bucket counting sort: 2 threads per run, copy+count fused ----------
__global__ __launch_bounds__(SORT_TB) void sortCSR_kernel(
        const int* __restrict__ stage, const int* __restrict__ bbcScan,
        int E, int nbuck, int chunk, int* __restrict__ srt,
        int* __restrict__ nodePtr, float* __restrict__ dinv, int N) {
    __shared__ int ldsRec[CAP];
    __shared__ unsigned char ranks[CAP];
    __shared__ int pref[NBLK];
    __shared__ int cnt[BNODES];
    __shared__ int cur[BNODES];
    int b = blockIdx.x;
    int t = threadIdx.x;
    int rt = t & (NBLK - 1);       // run index
    int hf = t >> 8;               // half: 0 or 1

    // run bounds for run rt (block-major bbcScan)
    int winS = min(rt * chunk, E);
    int runS = min(bbcScan[rt * nbuck + b], E);
    int runE = (b + 1 < nbuck) ? bbcScan[rt * nbuck + b + 1] : min((rt + 1) * chunk, E);
    runE = min(runE, E);
    int sz = runE - runS;

    // bucketStart = sum_rt (runS - winS)
    if (hf == 0) pref[rt] = runS - winS;
    __syncthreads();
    for (int off = NBLK / 2; off > 0; off >>= 1) {
        if (t < off) pref[t] += pref[t + off];
        __syncthreads();
    }
    int bucketStart = pref[0];
    __syncthreads();

    // inclusive scan of run sizes -> per-run LDS offset and total T
    if (hf == 0) pref[rt] = sz;
    __syncthreads();
    for (int off = 1; off < NBLK; off <<= 1) {
        int tmp = 0;
        if (t < NBLK && t >= off) tmp = pref[t - off];
        __syncthreads();
        if (t < NBLK) pref[t] += tmp;
        __syncthreads();
    }
    int runOff = pref[rt] - sz;
    int T = pref[NBLK - 1];

    // half split of the run
    int h0 = (sz + 1) >> 1;
    int myS  = runS + (hf ? h0 : 0);
    int myE  = hf ? runE : (runS + h0);
    int myOff = runOff + (hf ? h0 : 0);

    if (t < BNODES) cnt[t] = 0;
    __syncthreads();

    bool fit = (T <= CAP);
    if (fit) {
        // fused copy + count: atomicAdd rank assignment overlaps the global-load latency
        int k = myOff;
        for (int i = myS; i < myE; ++i, ++k) {
            int rec = stage[i];
            ldsRec[k] = rec;
            ranks[k] = (unsigned char)atomicAdd(&cnt[rec & (BNODES - 1)], 1);
        }
    } else {
        for (int i = myS; i < myE; ++i)
            atomicAdd(&cnt[stage[i] & (BNODES - 1)], 1);
    }
    __syncthreads();

    // exclusive scan of cnt[128]
    if (t < BNODES) cur[t] = cnt[t];
    __syncthreads();
    for (int off = 1; off < BNODES; off <<= 1) {
        int tmp = 0;
        if (t < BNODES && t >= off) tmp = cur[t - off];
        __syncthreads();
        if (t < BNODES) cur[t] += tmp;
        __syncthreads();
    }
    if (t < BNODES) {
        int excl = cur[t] - cnt[t];
        int v = b * BNODES + t;
        if (v < N) {
            nodePtr[v] = bucketStart + excl;
            dinv[v] = rsqrtf((float)cnt[t] + 1.0f);
        }
        cur[t] = bucketStart + excl;     // absolute base for positioned writes
    }
    if (b == nbuck - 1 && t == 0) nodePtr[N] = E;
    __syncthreads();

    if (fit) {
        // atomic-free positioned writes: pos = base[node] + rank
        int k = myOff;
        for (int i = myS; i < myE; ++i, ++k) {
            int rec = ldsRec[k];
            srt[cur[rec & (BNODES - 1)] + (int)ranks[k]] = rec >> BSHIFT;
        }
    } else {
        for (int i = myS; i < myE; ++i) {
            int rec = stage[i];
            int p = atomicAdd(&cur[rec & (BNODES - 1)], 1);
            srt[p] = rec >> BSHIFT;
        }
    }
}

// ---------- h1h = fp16( (x @ W1) * dinv[v] )  -- 3.2 MB, L2-resident ----------
__global__ void gemm1_kernel(const float* __restrict__ x, const float* __restrict__ W1,
                             const float* __restrict__ dinv, __half* __restrict__ h1h, int N) {
    __shared__ float sW[F_IN * H1];
    for (int i = threadIdx.x; i < F_IN * H1; i += blockDim.x) sW[i] = W1[i];
    __syncthreads();
    int v = blockIdx.x * blockDim.x + threadIdx.x;
    if (v >= N) return;
    float acc[H1];
#pragma unroll
    for (int j = 0; j < H1; ++j) acc[j] = 0.0f;
    const float4* xr = reinterpret_cast<const float4*>(x + (size_t)v * F_IN);
#pragma unroll 8
    for (int k4 = 0; k4 < F_IN / 4; ++k4) {
        float4 xv = xr[k4];
        const float* w = &sW[k4 * 4 * H1];
#pragma unroll
        for (int j = 0; j < H1; ++j) acc[j] += xv.x * w[j];
#pragma unroll
        for (int j = 0; j < H1; ++j) acc[j] += xv.y * w[H1 + j];
#pragma unroll
        for (int j = 0; j < H1; ++j) acc[j] += xv.z * w[2 * H1 + j];
#pragma unroll
        for (int j = 0; j < H1; ++j) acc[j] += xv.w * w[3 * H1 + j];
    }
    float di = dinv[v];
    alignas(16) __half2 hp[8];
#pragma unroll
    for (int q = 0; q < 8; ++q)
        hp[q] = __floats2half2_rn(acc[2 * q] * di, acc[2 * q + 1] * di);
    float4* ho = reinterpret_cast<float4*>(h1h + (size_t)v * H1);
    ho[0] = *reinterpret_cast<float4*>(&hp[0]);
    ho[1] = *reinterpret_cast<float4*>(&hp[4]);
}

// ---------- layer-1: 4 lanes/node, float4 (8-fp16) gathers + relu + GEMM2 fused ----------
#define AGG1_TB 512
__global__ __launch_bounds__(AGG1_TB) void agg1_kernel(
        const int* __restrict__ srt, const int* __restrict__ nodePtr,
        const __half* __restrict__ h1h, const float* __restrict__ dinv,
        const float* __restrict__ b1, const float* __restrict__ W2,
        __half* __restrict__ h2h, int N) {
    __shared__ float hrelu[BNODES][H1 + 1];
    __shared__ float sW[H1 * C2];
    __shared__ float sb[H1];
    for (int i = threadIdx.x; i < H1 * C2; i += AGG1_TB) sW[i] = W2[i];
    for (int i = threadIdx.x; i < H1; i += AGG1_TB) sb[i] = b1[i];
    __syncthreads();

    int base = blockIdx.x * BNODES;
    int vi = threadIdx.x >> 2;       // 128 groups = 128 nodes
    int ep = (threadIdx.x >> 1) & 1; // edge parity
    int q  = threadIdx.x & 1;        // row half (8 fp16 = 16 B)
    int v  = base + vi;

    if (v < N) {
        int p  = nodePtr[v];
        int pe = nodePtr[v + 1];
        float a0[8], a1[8];
#pragma unroll
        for (int k = 0; k < 8; ++k) { a0[k] = 0.f; a1[k] = 0.f; }
        int e = p + ep;
        for (; e + 2 < pe; e += 4) {
            int r0 = srt[e];
            int r1 = srt[e + 2];
            float4 p0 = *reinterpret_cast<const float4*>(h1h + (size_t)r0 * H1 + q * 8);
            float4 p1 = *reinterpret_cast<const float4*>(h1h + (size_t)r1 * H1 + q * 8);
            const __half2* h0 = reinterpret_cast<const __half2*>(&p0);
            const __half2* h1_ = reinterpret_cast<const __half2*>(&p1);
#pragma unroll
            for (int k = 0; k < 4; ++k) {
                float2 f0 = __half22float2(h0[k]);
                float2 f1 = __half22float2(h1_[k]);
                a0[2 * k] += f0.x; a0[2 * k + 1] += f0.y;
                a1[2 * k] += f1.x; a1[2 * k + 1] += f1.y;
            }
        }
        for (; e < pe; e += 2) {
            int r0 = srt[e];
            float4 p0 = *reinterpret_cast<const float4*>(h1h + (size_t)r0 * H1 + q * 8);
            const __half2* h0 = reinterpret_cast<const __half2*>(&p0);
#pragma unroll
            for (int k = 0; k < 4; ++k) {
                float2 f0 = __half22float2(h0[k]);
                a0[2 * k] += f0.x; a0[2 * k + 1] += f0.y;
            }
        }
#pragma unroll
        for (int k = 0; k < 8; ++k) a0[k] += a1[k];
#pragma unroll
        for (int k = 0; k < 8; ++k) a0[k] += __shfl_xor(a0[k], 2);

        if (ep == 0) {
            float4 ps = *reinterpret_cast<const float4*>(h1h + (size_t)v * H1 + q * 8);
            const __half2* hs = reinterpret_cast<const __half2*>(&ps);
            float di = dinv[v];
#pragma unroll
            for (int k = 0; k < 4; ++k) {
                float2 fs = __half22float2(hs[k]);
                int j0 = q * 8 + 2 * k, j1 = j0 + 1;
                hrelu[vi][j0] = fmaxf(di * (a0[2 * k] + fs.x) + sb[j0], 0.0f);
                hrelu[vi][j1] = fmaxf(di * (a0[2 * k + 1] + fs.y) + sb[j1], 0.0f);
            }
        }
    }
    __syncthreads();

    int j = threadIdx.x & 7;
    for (int vi2 = threadIdx.x >> 3; vi2 < BNODES; vi2 += (AGG1_TB >> 3)) {
        int v2 = base + vi2;
        if (v2 < N) {
            float dot = 0.0f;
#pragma unroll
            for (int k = 0; k < H1; ++k) dot += hrelu[vi2][k] * sW[k * C2 + j];
            h2h[(size_t)v2 * C2 + j] = __float2half(dot * dinv[v2]);
        }
    }
}

// ---------- layer-2: 2 lanes/node, float4 (8-fp16) gathers + log_softmax in-register ----------
#define AGG2_TB 256
__global__ __launch_bounds__(AGG2_TB) void agg2_kernel(
        const int* __restrict__ srt, const int* __restrict__ nodePtr,
        const __half* __restrict__ h2h, const float* __restrict__ dinv,
        const float* __restrict__ b2, float* __restrict__ out, int N) {
    int vi  = threadIdx.x >> 1;         // 128 nodes per block
    int par = threadIdx.x & 1;          // edge parity
    int v = blockIdx.x * (AGG2_TB / 2) + vi;
    if (v >= N) return;
    int p  = nodePtr[v];
    int pe = nodePtr[v + 1];
    float a0[8], a1[8];
#pragma unroll
    for (int k = 0; k < 8; ++k) { a0[k] = 0.f; a1[k] = 0.f; }
    int e = p + par;
    for (; e + 2 < pe; e += 4) {        // 2 edges in flight per lane
        int r0 = srt[e];
        int r1 = srt[e + 2];
        float4 p0 = *reinterpret_cast<const float4*>(h2h + (size_t)r0 * C2);
        float4 p1 = *reinterpret_cast<const float4*>(h2h + (size_t)r1 * C2);
        const __half2* h0 = reinterpret_cast<const __half2*>(&p0);
        const __half2* h1_ = reinterpret_cast<const __half2*>(&p1);
#pragma unroll
        for (int k = 0; k < 4; ++k) {
            float2 f0 = __half22float2(h0[k]);
            float2 f1 = __half22float2(h1_[k]);
            a0[2 * k] += f0.x; a0[2 * k + 1] += f0.y;
            a1[2 * k] += f1.x; a1[2 * k + 1] += f1.y;
        }
    }
    for (; e < pe; e += 2) {
        int r0 = srt[e];
        float4 p0 = *reinterpret_cast<const float4*>(h2h + (size_t)r0 * C2);
        const __half2* h0 = reinterpret_cast<const __half2*>(&p0);
#pragma unroll
        for (int k = 0; k < 4; ++k) {
            float2 f0 = __half22float2(h0[k]);
            a0[2 * k] += f0.x; a0[2 * k + 1] += f0.y;
        }
    }
#pragma unroll
    for (int k = 0; k < 8; ++k) a0[k] += a1[k];
    // merge parity partner (lane ^ 1)
#pragma unroll
    for (int k = 0; k < 8; ++k) a0[k] += __shfl_xor(a0[k], 1);
    if (par) return;

    float4 ps = *reinterpret_cast<const float4*>(h2h + (size_t)v * C2);
    const __half2* hs = reinterpret_cast<const __half2*>(&ps);
    float di = dinv[v];
    float z[C2];
#pragma unroll
    for (int k = 0; k < 4; ++k) {
        float2 fs = __half22float2(hs[k]);
        z[2 * k]     = di * (a0[2 * k] + fs.x) + b2[2 * k];
        z[2 * k + 1] = di * (a0[2 * k + 1] + fs.y) + b2[2 * k + 1];
    }
    float m = z[0];
#pragma unroll
    for (int j = 1; j < C2; ++j) m = fmaxf(m, z[j]);
    float s = 0.0f;
#pragma unroll
    for (int j = 0; j < C2; ++j) s += __expf(z[j] - m);
    float lse = m + logf(s);
    float4* o = reinterpret_cast<float4*>(out + (size_t)v * C2);
    o[0] = make_float4(z[0] - lse, z[1] - lse, z[2] - lse, z[3] - lse);
    o[1] = make_float4(z[4] - lse, z[5] - lse, z[6] - lse, z[7] - lse);
}

extern "C" void kernel_launch(void* const* d_in, const int* in_sizes, int n_in,
                              void* d_out, int out_size, void* d_ws, size_t ws_size,
                              hipStream_t stream) {
    const float* x  = (const float*)d_in[0];
    const int*   ei = (const int*)d_in[1];
    const float* W1 = (const float*)d_in[2];
    const float* b1 = (const float*)d_in[3];
    const float* W2 = (const float*)d_in[4];
    const float* b2 = (const float*)d_in[5];
    float* out = (float*)d_out;

    const int N = in_sizes[0] / F_IN;
    const int E = in_sizes[1] / 2;
    const int nbuck = (N + BNODES - 1) >> BSHIFT;        // 782
    const int M = NBLK * nbuck;                          // 256*782 (block-major)
    int chunk = (E + NBLK - 1) / NBLK;
    chunk = (chunk + 3) & ~3;                            // keep windows 16B-aligned

    // workspace layout (4B units); nodePtr padded to N+8 to keep h1h 16B-aligned
    int*    stage   = (int*)d_ws;                        // E
    int*    srt     = stage + E;                         // E
    int*    bbcScan = srt + E;                           // M
    int*    nodePtr = bbcScan + M;                       // N+8 (N+1 used)
    float*  dinv    = (float*)(nodePtr + N + 8);         // N
    __half* h1h     = (__half*)(dinv + N);               // 16N halves
    __half* h2h     = h1h + (size_t)16 * N;              // 8N halves

    const int TB = 256;

    binScatter2_kernel<<<NBLK, BIN_TB, 0, stream>>>(ei, E, chunk, nbuck, bbcScan, stage);
    sortCSR_kernel<<<nbuck, SORT_TB, 0, stream>>>(stage, bbcScan, E, nbuck, chunk, srt, nodePtr, dinv, N);
    gemm1_kernel<<<(N + TB - 1) / TB, TB, 0, stream>>>(x, W1, dinv, h1h, N);
    agg1_kernel<<<nbuck, AGG1_TB, 0, stream>>>(srt, nodePtr, h1h, dinv, b1, W2, h2h, N);
    agg2_kernel<<<(N + (AGG2_TB / 2) - 1) / (AGG2_TB / 2), AGG2_TB, 0, stream>>>(srt, nodePtr, h2h, dinv, b2, out, N);
}

// Round 19
// 116.317 us; speedup vs baseline: 1.1920x; 1.1920x over previous
//
#include <hip/hip_runtime.h>
#include <hip/hip_fp16.h>

#define F_IN 128
#define H1   16
#define C2   8
#define BSHIFT 7
#define BNODES 128            // nodes per bucket
#define MAXBUCK 1024          // LDS array bound (runtime nbuck=782)
#define NBLK 256              // binning windows (== threads in sortCSR)
#define BIN_TB 1024           // binScatter2 threads
#define CAP  6144             // sortCSR LDS record staging (avg bucket = 4096)
#define CHUNK_CAP 12800       // binScatter2 per-block edge capacity (chunk = 12500)

// ---------- merged binning: LDS-staged sort + COALESCED dump ----------
// Block blk owns stage window [blk*chunk, blk*chunk+csize). Records are
// bucket-sorted into LDS (cursor atomics give positions), then dumped to
// global with fully-coalesced streaming stores -- no scattered 4B stores.
__global__ __launch_bounds__(BIN_TB) void binScatter2_kernel(
        const int* __restrict__ ei, int E, int chunk, int nbuck,
        int* __restrict__ bbcScan, int* __restrict__ stage) {
    __shared__ int h[MAXBUCK];            // 4 KB   histogram -> cursors
    __shared__ int sc[512];               // 2 KB   scan buffer
    __shared__ int ldsStage[CHUNK_CAP];   // 51.2 KB block-local sorted records
    int t = threadIdx.x;
    int blk = blockIdx.x;
    int base = blk * chunk;
    int csize = max(0, min(chunk, E - base));
    int blkBase = base;

    for (int i = t; i < MAXBUCK; i += BIN_TB) h[i] = 0;
    __syncthreads();

    const int* colp = ei + E + base;
    const int* rowp = ei + base;
    bool al4 = ((E & 3) == 0) && ((base & 3) == 0) && ((csize & 3) == 0);
    bool fit = (csize <= CHUNK_CAP);

    // pass 1: histogram of destination buckets
    if (al4) {
        const int4* cv = reinterpret_cast<const int4*>(colp);
        int nv = csize >> 2;
        for (int i = t; i < nv; i += BIN_TB) {
            int4 c4 = cv[i];
            atomicAdd(&h[c4.x >> BSHIFT], 1);
            atomicAdd(&h[c4.y >> BSHIFT], 1);
            atomicAdd(&h[c4.z >> BSHIFT], 1);
            atomicAdd(&h[c4.w >> BSHIFT], 1);
        }
    } else {
        for (int i = t; i < csize; i += BIN_TB) atomicAdd(&h[colp[i] >> BSHIFT], 1);
    }
    __syncthreads();

    // in-block exclusive scan of h[0..1024); threads t<512 own entries 2t, 2t+1
    int e0 = 0, e1 = 0, psum = 0;
    if (t < 512) {
        e0 = h[2 * t]; e1 = h[2 * t + 1];
        psum = e0 + e1;
        sc[t] = psum;
    }
    __syncthreads();
    for (int off = 1; off < 512; off <<= 1) {
        int tmp = (t < 512 && t >= off) ? sc[t - off] : 0;
        __syncthreads();
        if (t < 512) sc[t] += tmp;
        __syncthreads();
    }
    if (t < 512) {
        int excl = sc[t] - psum;
        if (fit) {
            h[2 * t] = excl;                 // LOCAL cursors for LDS staging
            h[2 * t + 1] = excl + e0;
        } else {
            h[2 * t] = blkBase + excl;       // global cursors (fallback)
            h[2 * t + 1] = blkBase + excl + e0;
        }
        // publish run starts (always global positions)
        sc[t] = excl;                        // stash for publish below
    }
    __syncthreads();

    // publish run starts for sortCSR: bbcScan = blkBase + excl
    for (int b = t; b < nbuck; b += BIN_TB)
        bbcScan[blk * nbuck + b] = blkBase + (fit ? h[b] : (h[b] - blkBase));
    __syncthreads();

    // pass 2: cursor-atomic positioned writes
    if (fit) {
        // into LDS (scattered LDS is cheap), then coalesced dump
        if (al4) {
            const int4* cv = reinterpret_cast<const int4*>(colp);
            const int4* rv = reinterpret_cast<const int4*>(rowp);
            int nv = csize >> 2;
            for (int i = t; i < nv; i += BIN_TB) {
                int4 c4 = cv[i];
                int4 r4 = rv[i];
                int p0 = atomicAdd(&h[c4.x >> BSHIFT], 1);
                ldsStage[p0] = (r4.x << BSHIFT) | (c4.x & (BNODES - 1));
                int p1 = atomicAdd(&h[c4.y >> BSHIFT], 1);
                ldsStage[p1] = (r4.y << BSHIFT) | (c4.y & (BNODES - 1));
                int p2 = atomicAdd(&h[c4.z >> BSHIFT], 1);
                ldsStage[p2] = (r4.z << BSHIFT) | (c4.z & (BNODES - 1));
                int p3 = atomicAdd(&h[c4.w >> BSHIFT], 1);
                ldsStage[p3] = (r4.w << BSHIFT) | (c4.w & (BNODES - 1));
            }
        } else {
            for (int i = t; i < csize; i += BIN_TB) {
                int r = rowp[i];
                int c = colp[i];
                int p = atomicAdd(&h[c >> BSHIFT], 1);
                ldsStage[p] = (r << BSHIFT) | (c & (BNODES - 1));
            }
        }
        __syncthreads();
        // coalesced dump: 1024 threads stream the sorted block
        for (int i = t; i < csize; i += BIN_TB)
            stage[base + i] = ldsStage[i];
    } else {
        // fallback: scattered global positioned writes (correct for any csize)
        if (al4) {
            const int4* cv = reinterpret_cast<const int4*>(colp);
            const int4* rv = reinterpret_cast<const int4*>(rowp);
            int nv = csize >> 2;
            for (int i = t; i < nv; i += BIN_TB) {
                int4 c4 = cv[i];
                int4 r4 = rv[i];
                int p0 = atomicAdd(&h[c4.x >> BSHIFT], 1);
                stage[p0] = (r4.x << BSHIFT) | (c4.x & (BNODES - 1));
                int p1 = atomicAdd(&h[c4.y >> BSHIFT], 1);
                stage[p1] = (r4.y << BSHIFT) | (c4.y & (BNODES - 1));
                int p2 = atomicAdd(&h[c4.z >> BSHIFT], 1);
                stage[p2] = (r4.z << BSHIFT) | (c4.z & (BNODES - 1));
                int p3 = atomicAdd(&h[c4.w >> BSHIFT], 1);
                stage[p3] = (r4.w << BSHIFT) | (c4.w & (BNODES - 1));
            }
        } else {
            for (int i = t; i < csize; i += BIN_TB) {
                int r = rowp[i];
                int c = colp[i];
                int p = atomicAdd(&h[c >> BSHIFT], 1);
                stage[p] = (r << BSHIFT) | (c & (BNODES - 1));
            }
        }
    }
}

// ---------- within-bucket counting sort: copy+count fused (rank in LDS), positioned writes ----------
__global__ __launch_bounds__(NBLK) void sortCSR_kernel(
        const int* __restrict__ stage, const int* __restrict__ bbcScan,
        int E, int nbuck, int chunk, int* __restrict__ srt,
        int* __restrict__ nodePtr, float* __restrict__ dinv, int N) {
    __shared__ int ldsRec[CAP];
    __shared__ unsigned char ranks[CAP];
    __shared__ int pref[NBLK];
    __shared__ int cnt[BNODES];
    __shared__ int cur[BNODES];
    int b = blockIdx.x;
    int t = threadIdx.x;

    int winS = min(t * chunk, E);
    int runS = min(bbcScan[t * nbuck + b], E);
    int runE = (b + 1 < nbuck) ? bbcScan[t * nbuck + b + 1] : min((t + 1) * chunk, E);
    runE = min(runE, E);
    int sz = runE - runS;

    // bucketStart = sum_t (runS - winS)
    pref[t] = runS - winS;
    __syncthreads();
    for (int off = NBLK / 2; off > 0; off >>= 1) {
        if (t < off) pref[t] += pref[t + off];
        __syncthreads();
    }
    int bucketStart = pref[0];
    __syncthreads();

    // inclusive scan of run sizes -> per-run LDS offset and total T
    pref[t] = sz;
    __syncthreads();
    for (int off = 1; off < NBLK; off <<= 1) {
        int tmp = (t >= off) ? pref[t - off] : 0;
        __syncthreads();
        pref[t] += tmp;
        __syncthreads();
    }
    int myOff = pref[t] - sz;
    int T = pref[NBLK - 1];

    if (t < BNODES) cnt[t] = 0;
    __syncthreads();

    bool fit = (T <= CAP);
    if (fit) {
        // fused copy + count: atomicAdd rank assignment overlaps the global-load latency
        for (int i = 0; i < sz; ++i) {
            int rec = stage[runS + i];
            ldsRec[myOff + i] = rec;
            ranks[myOff + i] = (unsigned char)atomicAdd(&cnt[rec & (BNODES - 1)], 1);
        }
    } else {
        for (int i = runS; i < runE; ++i)
            atomicAdd(&cnt[stage[i] & (BNODES - 1)], 1);
    }
    __syncthreads();

    // exclusive scan of cnt[128]
    if (t < BNODES) cur[t] = cnt[t];
    __syncthreads();
    for (int off = 1; off < BNODES; off <<= 1) {
        int tmp = 0;
        if (t < BNODES && t >= off) tmp = cur[t - off];
        __syncthreads();
        if (t < BNODES) cur[t] += tmp;
        __syncthreads();
    }
    if (t < BNODES) {
        int excl = cur[t] - cnt[t];
        int v = b * BNODES + t;
        if (v < N) {
            nodePtr[v] = bucketStart + excl;
            dinv[v] = rsqrtf((float)cnt[t] + 1.0f);
        }
        cur[t] = bucketStart + excl;     // absolute base for positioned writes
    }
    if (b == nbuck - 1 && t == 0) nodePtr[N] = E;
    __syncthreads();

    if (fit) {
        // atomic-free positioned writes: pos = base[node] + rank
        for (int i = 0; i < sz; ++i) {
            int rec = ldsRec[myOff + i];
            srt[cur[rec & (BNODES - 1)] + (int)ranks[myOff + i]] = rec >> BSHIFT;
        }
    } else {
        for (int i = runS; i < runE; ++i) {
            int rec = stage[i];
            int p = atomicAdd(&cur[rec & (BNODES - 1)], 1);
            srt[p] = rec >> BSHIFT;
        }
    }
}

// ---------- h1h = fp16( (x @ W1) * dinv[v] )  -- 3.2 MB, L2-resident ----------
__global__ void gemm1_kernel(const float* __restrict__ x, const float* __restrict__ W1,
                             const float* __restrict__ dinv, __half* __restrict__ h1h, int N) {
    __shared__ float sW[F_IN * H1];
    for (int i = threadIdx.x; i < F_IN * H1; i += blockDim.x) sW[i] = W1[i];
    __syncthreads();
    int v = blockIdx.x * blockDim.x + threadIdx.x;
    if (v >= N) return;
    float acc[H1];
#pragma unroll
    for (int j = 0; j < H1; ++j) acc[j] = 0.0f;
    const float4* xr = reinterpret_cast<const float4*>(x + (size_t)v * F_IN);
#pragma unroll 8
    for (int k4 = 0; k4 < F_IN / 4; ++k4) {
        float4 xv = xr[k4];
        const float* w = &sW[k4 * 4 * H1];
#pragma unroll
        for (int j = 0; j < H1; ++j) acc[j] += xv.x * w[j];
#pragma unroll
        for (int j = 0; j < H1; ++j) acc[j] += xv.y * w[H1 + j];
#pragma unroll
        for (int j = 0; j < H1; ++j) acc[j] += xv.z * w[2 * H1 + j];
#pragma unroll
        for (int j = 0; j < H1; ++j) acc[j] += xv.w * w[3 * H1 + j];
    }
    float di = dinv[v];
    alignas(16) __half2 hp[8];
#pragma unroll
    for (int q = 0; q < 8; ++q)
        hp[q] = __floats2half2_rn(acc[2 * q] * di, acc[2 * q + 1] * di);
    float4* ho = reinterpret_cast<float4*>(h1h + (size_t)v * H1);
    ho[0] = *reinterpret_cast<float4*>(&hp[0]);
    ho[1] = *reinterpret_cast<float4*>(&hp[4]);
}

// ---------- layer-1: 4 lanes/node, float4 (8-fp16) gathers + relu + GEMM2 fused ----------
#define AGG1_TB 512
__global__ __launch_bounds__(AGG1_TB) void agg1_kernel(
        const int* __restrict__ srt, const int* __restrict__ nodePtr,
        const __half* __restrict__ h1h, const float* __restrict__ dinv,
        const float* __restrict__ b1, const float* __restrict__ W2,
        __half* __restrict__ h2h, int N) {
    __shared__ float hrelu[BNODES][H1 + 1];
    __shared__ float sW[H1 * C2];
    __shared__ float sb[H1];
    for (int i = threadIdx.x; i < H1 * C2; i += AGG1_TB) sW[i] = W2[i];
    for (int i = threadIdx.x; i < H1; i += AGG1_TB) sb[i] = b1[i];
    __syncthreads();

    int base = blockIdx.x * BNODES;
    int vi = threadIdx.x >> 2;       // 128 groups = 128 nodes
    int ep = (threadIdx.x >> 1) & 1; // edge parity
    int q  = threadIdx.x & 1;        // row half (8 fp16 = 16 B)
    int v  = base + vi;

    if (v < N) {
        int p  = nodePtr[v];
        int pe = nodePtr[v + 1];
        float a0[8], a1[8];
#pragma unroll
        for (int k = 0; k < 8; ++k) { a0[k] = 0.f; a1[k] = 0.f; }
        int e = p + ep;
        for (; e + 2 < pe; e += 4) {
            int r0 = srt[e];
            int r1 = srt[e + 2];
            float4 p0 = *reinterpret_cast<const float4*>(h1h + (size_t)r0 * H1 + q * 8);
            float4 p1 = *reinterpret_cast<const float4*>(h1h + (size_t)r1 * H1 + q * 8);
            const __half2* h0 = reinterpret_cast<const __half2*>(&p0);
            const __half2* h1_ = reinterpret_cast<const __half2*>(&p1);
#pragma unroll
            for (int k = 0; k < 4; ++k) {
                float2 f0 = __half22float2(h0[k]);
                float2 f1 = __half22float2(h1_[k]);
                a0[2 * k] += f0.x; a0[2 * k + 1] += f0.y;
                a1[2 * k] += f1.x; a1[2 * k + 1] += f1.y;
            }
        }
        for (; e < pe; e += 2) {
            int r0 = srt[e];
            float4 p0 = *reinterpret_cast<const float4*>(h1h + (size_t)r0 * H1 + q * 8);
            const __half2* h0 = reinterpret_cast<const __half2*>(&p0);
#pragma unroll
            for (int k = 0; k < 4; ++k) {
                float2 f0 = __half22float2(h0[k]);
                a0[2 * k] += f0.x; a0[2 * k + 1] += f0.y;
            }
        }
#pragma unroll
        for (int k = 0; k < 8; ++k) a0[k] += a1[k];
#pragma unroll
        for (int k = 0; k < 8; ++k) a0[k] += __shfl_xor(a0[k], 2);

        if (ep == 0) {
            float4 ps = *reinterpret_cast<const float4*>(h1h + (size_t)v * H1 + q * 8);
            const __half2* hs = reinterpret_cast<const __half2*>(&ps);
            float di = dinv[v];
#pragma unroll
            for (int k = 0; k < 4; ++k) {
                float2 fs = __half22float2(hs[k]);
                int j0 = q * 8 + 2 * k, j1 = j0 + 1;
                hrelu[vi][j0] = fmaxf(di * (a0[2 * k] + fs.x) + sb[j0], 0.0f);
                hrelu[vi][j1] = fmaxf(di * (a0[2 * k + 1] + fs.y) + sb[j1], 0.0f);
            }
        }
    }
    __syncthreads();

    int j = threadIdx.x & 7;
    for (int vi2 = threadIdx.x >> 3; vi2 < BNODES; vi2 += (AGG1_TB >> 3)) {
        int v2 = base + vi2;
        if (v2 < N) {
            float dot = 0.0f;
#pragma unroll
            for (int k = 0; k < H1; ++k) dot += hrelu[vi2][k] * sW[k * C2 + j];
            h2h[(size_t)v2 * C2 + j] = __float2half(dot * dinv[v2]);
        }
    }
}

// ---------- layer-2: 2 lanes/node, float4 (8-fp16) gathers + log_softmax in-register ----------
#define AGG2_TB 256
__global__ __launch_bounds__(AGG2_TB) void agg2_kernel(
        const int* __restrict__ srt, const int* __restrict__ nodePtr,
        const __half* __restrict__ h2h, const float* __restrict__ dinv,
        const float* __restrict__ b2, float* __restrict__ out, int N) {
    int vi  = threadIdx.x >> 1;         // 128 nodes per block
    int par = threadIdx.x & 1;          // edge parity
    int v = blockIdx.x * (AGG2_TB / 2) + vi;
    if (v >= N) return;
    int p  = nodePtr[v];
    int pe = nodePtr[v + 1];
    float a0[8], a1[8];
#pragma unroll
    for (int k = 0; k < 8; ++k) { a0[k] = 0.f; a1[k] = 0.f; }
    int e = p + par;
    for (; e + 2 < pe; e += 4) {        // 2 edges in flight per lane
        int r0 = srt[e];
        int r1 = srt[e + 2];
        float4 p0 = *reinterpret_cast<const float4*>(h2h + (size_t)r0 * C2);
        float4 p1 = *reinterpret_cast<const float4*>(h2h + (size_t)r1 * C2);
        const __half2* h0 = reinterpret_cast<const __half2*>(&p0);
        const __half2* h1_ = reinterpret_cast<const __half2*>(&p1);
#pragma unroll
        for (int k = 0; k < 4; ++k) {
            float2 f0 = __half22float2(h0[k]);
            float2 f1 = __half22float2(h1_[k]);
            a0[2 * k] += f0.x; a0[2 * k + 1] += f0.y;
            a1[2 * k] += f1.x; a1[2 * k + 1] += f1.y;
        }
    }
    for (; e < pe; e += 2) {
        int r0 = srt[e];
        float4 p0 = *reinterpret_cast<const float4*>(h2h + (size_t)r0 * C2);
        const __half2* h0 = reinterpret_cast<const __half2*>(&p0);
#pragma unroll
        for (int k = 0; k < 4; ++k) {
            float2 f0 = __half22float2(h0[k]);
            a0[2 * k] += f0.x; a0[2 * k + 1] += f0.y;
        }
    }
#pragma unroll
    for (int k = 0; k < 8; ++k) a0[k] += a1[k];
    // merge parity partner (lane ^ 1)
#pragma unroll
    for (int k = 0; k < 8; ++k) a0[k] += __shfl_xor(a0[k], 1);
    if (par) return;

    float4 ps = *reinterpret_cast<const float4*>(h2h + (size_t)v * C2);
    const __half2* hs = reinterpret_cast<const __half2*>(&ps);
    float di = dinv[v];
    float z[C2];
#pragma unroll
    for (int k = 0; k < 4; ++k) {
        float2 fs = __half22float2(hs[k]);
        z[2 * k]     = di * (a0[2 * k] + fs.x) + b2[2 * k];
        z[2 * k + 1] = di * (a0[2 * k + 1] + fs.y) + b2[2 * k + 1];
    }
    float m = z[0];
#pragma unroll
    for (int j = 1; j < C2; ++j) m = fmaxf(m, z[j]);
    float s = 0.0f;
#pragma unroll
    for (int j = 0; j < C2; ++j) s += __expf(z[j] - m);
    float lse = m + logf(s);
    float4* o = reinterpret_cast<float4*>(out + (size_t)v * C2);
    o[0] = make_float4(z[0] - lse, z[1] - lse, z[2] - lse, z[3] - lse);
    o[1] = make_float4(z[4] - lse, z[5] - lse, z[6] - lse, z[7] - lse);
}

extern "C" void kernel_launch(void* const* d_in, const int* in_sizes, int n_in,
                              void* d_out, int out_size, void* d_ws, size_t ws_size,
                              hipStream_t stream) {
    const float* x  = (const float*)d_in[0];
    const int*   ei = (const int*)d_in[1];
    const float* W1 = (const float*)d_in[2];
    const float* b1 = (const float*)d_in[3];
    const float* W2 = (const float*)d_in[4];
    const float* b2 = (const float*)d_in[5];
    float* out = (float*)d_out;

    const int N = in_sizes[0] / F_IN;
    const int E = in_sizes[1] / 2;
    const int nbuck = (N + BNODES - 1) >> BSHIFT;        // 782
    const int M = NBLK * nbuck;                          // 256*782 (block-major)
    int chunk = (E + NBLK - 1) / NBLK;
    chunk = (chunk + 3) & ~3;                            // keep windows 16B-aligned

    // workspace layout (4B units); nodePtr padded to N+8 to keep h1h 16B-aligned
    int*    stage   = (int*)d_ws;                        // E
    int*    srt     = stage + E;                         // E
    int*    bbcScan = srt + E;                           // M
    int*    nodePtr = bbcScan + M;                       // N+8 (N+1 used)
    float*  dinv    = (float*)(nodePtr + N + 8);         // N
    __half* h1h     = (__half*)(dinv + N);               // 16N halves
    __half* h2h     = h1h + (size_t)16 * N;              // 8N halves

    const int TB = 256;

    binScatter2_kernel<<<NBLK, BIN_TB, 0, stream>>>(ei, E, chunk, nbuck, bbcScan, stage);
    sortCSR_kernel<<<nbuck, NBLK, 0, stream>>>(stage, bbcScan, E, nbuck, chunk, srt, nodePtr, dinv, N);
    gemm1_kernel<<<(N + TB - 1) / TB, TB, 0, stream>>>(x, W1, dinv, h1h, N);
    agg1_kernel<<<nbuck, AGG1_TB, 0, stream>>>(srt, nodePtr, h1h, dinv, b1, W2, h2h, N);
    agg2_kernel<<<(N + (AGG2_TB / 2) - 1) / (AGG2_TB / 2), AGG2_TB, 0, stream>>>(srt, nodePtr, h2h, dinv, b2, out, N);
}

// Round 20
// 113.359 us; speedup vs baseline: 1.2231x; 1.0261x over previous
//
#include <hip/hip_runtime.h>
#include <hip/hip_fp16.h>

#define F_IN 128
#define H1   16
#define C2   8
#define BSHIFT 7
#define BNODES 128            // nodes per bucket
#define MAXBUCK 1024          // LDS array bound (runtime nbuck=782)
#define NBLK 256              // binning windows (== threads in sortCSR)
#define BIN_TB 1024           // binScatter2 threads
#define CAP  6144             // sortCSR LDS record staging (avg bucket = 4096)
#define CHUNK_CAP 12800       // binScatter2 per-block edge capacity (chunk = 12500)
#define SRCMASK 0x1FFFF       // 17-bit source id (N < 131072)

// ---------- merged binning: LDS-staged sort + COALESCED dump ----------
__global__ __launch_bounds__(BIN_TB) void binScatter2_kernel(
        const int* __restrict__ ei, int E, int chunk, int nbuck,
        int* __restrict__ bbcScan, int* __restrict__ stage) {
    __shared__ int h[MAXBUCK];            // 4 KB   histogram -> cursors
    __shared__ int sc[512];               // 2 KB   scan buffer
    __shared__ int ldsStage[CHUNK_CAP];   // 51.2 KB block-local sorted records
    int t = threadIdx.x;
    int blk = blockIdx.x;
    int base = blk * chunk;
    int csize = max(0, min(chunk, E - base));
    int blkBase = base;

    for (int i = t; i < MAXBUCK; i += BIN_TB) h[i] = 0;
    __syncthreads();

    const int* colp = ei + E + base;
    const int* rowp = ei + base;
    bool al4 = ((E & 3) == 0) && ((base & 3) == 0) && ((csize & 3) == 0);
    bool fit = (csize <= CHUNK_CAP);

    // pass 1: histogram of destination buckets
    if (al4) {
        const int4* cv = reinterpret_cast<const int4*>(colp);
        int nv = csize >> 2;
        for (int i = t; i < nv; i += BIN_TB) {
            int4 c4 = cv[i];
            atomicAdd(&h[c4.x >> BSHIFT], 1);
            atomicAdd(&h[c4.y >> BSHIFT], 1);
            atomicAdd(&h[c4.z >> BSHIFT], 1);
            atomicAdd(&h[c4.w >> BSHIFT], 1);
        }
    } else {
        for (int i = t; i < csize; i += BIN_TB) atomicAdd(&h[colp[i] >> BSHIFT], 1);
    }
    __syncthreads();

    // in-block exclusive scan of h[0..1024); threads t<512 own entries 2t, 2t+1
    int e0 = 0, e1 = 0, psum = 0;
    if (t < 512) {
        e0 = h[2 * t]; e1 = h[2 * t + 1];
        psum = e0 + e1;
        sc[t] = psum;
    }
    __syncthreads();
    for (int off = 1; off < 512; off <<= 1) {
        int tmp = (t < 512 && t >= off) ? sc[t - off] : 0;
        __syncthreads();
        if (t < 512) sc[t] += tmp;
        __syncthreads();
    }
    if (t < 512) {
        int excl = sc[t] - psum;
        if (fit) {
            h[2 * t] = excl;                 // LOCAL cursors for LDS staging
            h[2 * t + 1] = excl + e0;
        } else {
            h[2 * t] = blkBase + excl;       // global cursors (fallback)
            h[2 * t + 1] = blkBase + excl + e0;
        }
    }
    __syncthreads();

    // publish run starts for sortCSR: bbcScan = blkBase + excl
    for (int b = t; b < nbuck; b += BIN_TB)
        bbcScan[blk * nbuck + b] = blkBase + (fit ? h[b] : (h[b] - blkBase));
    __syncthreads();

    // pass 2: cursor-atomic positioned writes
    if (fit) {
        if (al4) {
            const int4* cv = reinterpret_cast<const int4*>(colp);
            const int4* rv = reinterpret_cast<const int4*>(rowp);
            int nv = csize >> 2;
            for (int i = t; i < nv; i += BIN_TB) {
                int4 c4 = cv[i];
                int4 r4 = rv[i];
                int p0 = atomicAdd(&h[c4.x >> BSHIFT], 1);
                ldsStage[p0] = (r4.x << BSHIFT) | (c4.x & (BNODES - 1));
                int p1 = atomicAdd(&h[c4.y >> BSHIFT], 1);
                ldsStage[p1] = (r4.y << BSHIFT) | (c4.y & (BNODES - 1));
                int p2 = atomicAdd(&h[c4.z >> BSHIFT], 1);
                ldsStage[p2] = (r4.z << BSHIFT) | (c4.z & (BNODES - 1));
                int p3 = atomicAdd(&h[c4.w >> BSHIFT], 1);
                ldsStage[p3] = (r4.w << BSHIFT) | (c4.w & (BNODES - 1));
            }
        } else {
            for (int i = t; i < csize; i += BIN_TB) {
                int r = rowp[i];
                int c = colp[i];
                int p = atomicAdd(&h[c >> BSHIFT], 1);
                ldsStage[p] = (r << BSHIFT) | (c & (BNODES - 1));
            }
        }
        __syncthreads();
        for (int i = t; i < csize; i += BIN_TB)
            stage[base + i] = ldsStage[i];
    } else {
        if (al4) {
            const int4* cv = reinterpret_cast<const int4*>(colp);
            const int4* rv = reinterpret_cast<const int4*>(rowp);
            int nv = csize >> 2;
            for (int i = t; i < nv; i += BIN_TB) {
                int4 c4 = cv[i];
                int4 r4 = rv[i];
                int p0 = atomicAdd(&h[c4.x >> BSHIFT], 1);
                stage[p0] = (r4.x << BSHIFT) | (c4.x & (BNODES - 1));
                int p1 = atomicAdd(&h[c4.y >> BSHIFT], 1);
                stage[p1] = (r4.y << BSHIFT) | (c4.y & (BNODES - 1));
                int p2 = atomicAdd(&h[c4.z >> BSHIFT], 1);
                stage[p2] = (r4.z << BSHIFT) | (c4.z & (BNODES - 1));
                int p3 = atomicAdd(&h[c4.w >> BSHIFT], 1);
                stage[p3] = (r4.w << BSHIFT) | (c4.w & (BNODES - 1));
            }
        } else {
            for (int i = t; i < csize; i += BIN_TB) {
                int r = rowp[i];
                int c = colp[i];
                int p = atomicAdd(&h[c >> BSHIFT], 1);
                stage[p] = (r << BSHIFT) | (c & (BNODES - 1));
            }
        }
    }
}

// ---------- within-bucket counting sort: rank packed in rec high byte,
// LDS-local positioned scatter + COALESCED srt dump ----------
__global__ __launch_bounds__(NBLK) void sortCSR_kernel(
        const int* __restrict__ stage, const int* __restrict__ bbcScan,
        int E, int nbuck, int chunk, int* __restrict__ srt,
        int* __restrict__ nodePtr, float* __restrict__ dinv, int N) {
    __shared__ int ldsRec[CAP];       // 24.6 KB: rec | (rank<<24)
    __shared__ int ldsSorted[CAP];    // 24.6 KB: sorted source ids
    __shared__ int pref[NBLK];
    __shared__ int cnt[BNODES];
    __shared__ int cur[BNODES];
    int b = blockIdx.x;
    int t = threadIdx.x;

    int winS = min(t * chunk, E);
    int runS = min(bbcScan[t * nbuck + b], E);
    int runE = (b + 1 < nbuck) ? bbcScan[t * nbuck + b + 1] : min((t + 1) * chunk, E);
    runE = min(runE, E);
    int sz = runE - runS;

    // bucketStart = sum_t (runS - winS)
    pref[t] = runS - winS;
    __syncthreads();
    for (int off = NBLK / 2; off > 0; off >>= 1) {
        if (t < off) pref[t] += pref[t + off];
        __syncthreads();
    }
    int bucketStart = pref[0];
    __syncthreads();

    // inclusive scan of run sizes -> per-run LDS offset and total T
    pref[t] = sz;
    __syncthreads();
    for (int off = 1; off < NBLK; off <<= 1) {
        int tmp = (t >= off) ? pref[t - off] : 0;
        __syncthreads();
        pref[t] += tmp;
        __syncthreads();
    }
    int myOff = pref[t] - sz;
    int T = pref[NBLK - 1];

    if (t < BNODES) cnt[t] = 0;
    __syncthreads();

    bool fit = (T <= CAP);
    if (fit) {
        // fused copy + count; rank rides in bits 24..31 of the record
        for (int i = 0; i < sz; ++i) {
            int rec = stage[runS + i];
            int rank = atomicAdd(&cnt[rec & (BNODES - 1)], 1);
            ldsRec[myOff + i] = rec | (rank << 24);
        }
    } else {
        for (int i = runS; i < runE; ++i)
            atomicAdd(&cnt[stage[i] & (BNODES - 1)], 1);
    }
    __syncthreads();

    // exclusive scan of cnt[128]
    if (t < BNODES) cur[t] = cnt[t];
    __syncthreads();
    for (int off = 1; off < BNODES; off <<= 1) {
        int tmp = 0;
        if (t < BNODES && t >= off) tmp = cur[t - off];
        __syncthreads();
        if (t < BNODES) cur[t] += tmp;
        __syncthreads();
    }
    if (t < BNODES) {
        int excl = cur[t] - cnt[t];
        int v = b * BNODES + t;
        if (v < N) {
            nodePtr[v] = bucketStart + excl;
            dinv[v] = rsqrtf((float)cnt[t] + 1.0f);
        }
        cur[t] = excl;                   // LOCAL base for LDS positioned writes
    }
    if (b == nbuck - 1 && t == 0) nodePtr[N] = E;
    __syncthreads();

    if (fit) {
        // positioned writes into LDS (cheap scatter), then coalesced dump
        for (int i = 0; i < sz; ++i) {
            int rec = ldsRec[myOff + i];
            int node = rec & (BNODES - 1);
            int rank = (int)((unsigned int)rec >> 24);
            ldsSorted[cur[node] + rank] = (rec >> BSHIFT) & SRCMASK;
        }
        __syncthreads();
        for (int i = t; i < T; i += NBLK)
            srt[bucketStart + i] = ldsSorted[i];
    } else {
        for (int i = runS; i < runE; ++i) {
            int rec = stage[i];
            int p = atomicAdd(&cur[rec & (BNODES - 1)], 1);
            srt[bucketStart + p] = rec >> BSHIFT;
        }
    }
}

// ---------- h1h = fp16( (x @ W1) * dinv[v] )  -- 3.2 MB, L2-resident ----------
__global__ void gemm1_kernel(const float* __restrict__ x, const float* __restrict__ W1,
                             const float* __restrict__ dinv, __half* __restrict__ h1h, int N) {
    __shared__ float sW[F_IN * H1];
    for (int i = threadIdx.x; i < F_IN * H1; i += blockDim.x) sW[i] = W1[i];
    __syncthreads();
    int v = blockIdx.x * blockDim.x + threadIdx.x;
    if (v >= N) return;
    float acc[H1];
#pragma unroll
    for (int j = 0; j < H1; ++j) acc[j] = 0.0f;
    const float4* xr = reinterpret_cast<const float4*>(x + (size_t)v * F_IN);
#pragma unroll 8
    for (int k4 = 0; k4 < F_IN / 4; ++k4) {
        float4 xv = xr[k4];
        const float* w = &sW[k4 * 4 * H1];
#pragma unroll
        for (int j = 0; j < H1; ++j) acc[j] += xv.x * w[j];
#pragma unroll
        for (int j = 0; j < H1; ++j) acc[j] += xv.y * w[H1 + j];
#pragma unroll
        for (int j = 0; j < H1; ++j) acc[j] += xv.z * w[2 * H1 + j];
#pragma unroll
        for (int j = 0; j < H1; ++j) acc[j] += xv.w * w[3 * H1 + j];
    }
    float di = dinv[v];
    alignas(16) __half2 hp[8];
#pragma unroll
    for (int q = 0; q < 8; ++q)
        hp[q] = __floats2half2_rn(acc[2 * q] * di, acc[2 * q + 1] * di);
    float4* ho = reinterpret_cast<float4*>(h1h + (size_t)v * H1);
    ho[0] = *reinterpret_cast<float4*>(&hp[0]);
    ho[1] = *reinterpret_cast<float4*>(&hp[4]);
}

// ---------- layer-1: 4 lanes/node, float4 (8-fp16) gathers + relu + GEMM2 fused ----------
#define AGG1_TB 512
__global__ __launch_bounds__(AGG1_TB) void agg1_kernel(
        const int* __restrict__ srt, const int* __restrict__ nodePtr,
        const __half* __restrict__ h1h, const float* __restrict__ dinv,
        const float* __restrict__ b1, const float* __restrict__ W2,
        __half* __restrict__ h2h, int N) {
    __shared__ float hrelu[BNODES][H1 + 1];
    __shared__ float sW[H1 * C2];
    __shared__ float sb[H1];
    for (int i = threadIdx.x; i < H1 * C2; i += AGG1_TB) sW[i] = W2[i];
    for (int i = threadIdx.x; i < H1; i += AGG1_TB) sb[i] = b1[i];
    __syncthreads();

    int base = blockIdx.x * BNODES;
    int vi = threadIdx.x >> 2;       // 128 groups = 128 nodes
    int ep = (threadIdx.x >> 1) & 1; // edge parity
    int q  = threadIdx.x & 1;        // row half (8 fp16 = 16 B)
    int v  = base + vi;

    if (v < N) {
        int p  = nodePtr[v];
        int pe = nodePtr[v + 1];
        float a0[8], a1[8];
#pragma unroll
        for (int k = 0; k < 8; ++k) { a0[k] = 0.f; a1[k] = 0.f; }
        int e = p + ep;
        for (; e + 2 < pe; e += 4) {
            int r0 = srt[e];
            int r1 = srt[e + 2];
            float4 p0 = *reinterpret_cast<const float4*>(h1h + (size_t)r0 * H1 + q * 8);
            float4 p1 = *reinterpret_cast<const float4*>(h1h + (size_t)r1 * H1 + q * 8);
            const __half2* h0 = reinterpret_cast<const __half2*>(&p0);
            const __half2* h1_ = reinterpret_cast<const __half2*>(&p1);
#pragma unroll
            for (int k = 0; k < 4; ++k) {
                float2 f0 = __half22float2(h0[k]);
                float2 f1 = __half22float2(h1_[k]);
                a0[2 * k] += f0.x; a0[2 * k + 1] += f0.y;
                a1[2 * k] += f1.x; a1[2 * k + 1] += f1.y;
            }
        }
        for (; e < pe; e += 2) {
            int r0 = srt[e];
            float4 p0 = *reinterpret_cast<const float4*>(h1h + (size_t)r0 * H1 + q * 8);
            const __half2* h0 = reinterpret_cast<const __half2*>(&p0);
#pragma unroll
            for (int k = 0; k < 4; ++k) {
                float2 f0 = __half22float2(h0[k]);
                a0[2 * k] += f0.x; a0[2 * k + 1] += f0.y;
            }
        }
#pragma unroll
        for (int k = 0; k < 8; ++k) a0[k] += a1[k];
#pragma unroll
        for (int k = 0; k < 8; ++k) a0[k] += __shfl_xor(a0[k], 2);

        if (ep == 0) {
            float4 ps = *reinterpret_cast<const float4*>(h1h + (size_t)v * H1 + q * 8);
            const __half2* hs = reinterpret_cast<const __half2*>(&ps);
            float di = dinv[v];
#pragma unroll
            for (int k = 0; k < 4; ++k) {
                float2 fs = __half22float2(hs[k]);
                int j0 = q * 8 + 2 * k, j1 = j0 + 1;
                hrelu[vi][j0] = fmaxf(di * (a0[2 * k] + fs.x) + sb[j0], 0.0f);
                hrelu[vi][j1] = fmaxf(di * (a0[2 * k + 1] + fs.y) + sb[j1], 0.0f);
            }
        }
    }
    __syncthreads();

    int j = threadIdx.x & 7;
    for (int vi2 = threadIdx.x >> 3; vi2 < BNODES; vi2 += (AGG1_TB >> 3)) {
        int v2 = base + vi2;
        if (v2 < N) {
            float dot = 0.0f;
#pragma unroll
            for (int k = 0; k < H1; ++k) dot += hrelu[vi2][k] * sW[k * C2 + j];
            h2h[(size_t)v2 * C2 + j] = __float2half(dot * dinv[v2]);
        }
    }
}

// ---------- layer-2: 2 lanes/node, float4 (8-fp16) gathers + log_softmax in-register ----------
#define AGG2_TB 256
__global__ __launch_bounds__(AGG2_TB) void agg2_kernel(
        const int* __restrict__ srt, const int* __restrict__ nodePtr,
        const __half* __restrict__ h2h, const float* __restrict__ dinv,
        const float* __restrict__ b2, float* __restrict__ out, int N) {
    int vi  = threadIdx.x >> 1;         // 128 nodes per block
    int par = threadIdx.x & 1;          // edge parity
    int v = blockIdx.x * (AGG2_TB / 2) + vi;
    if (v >= N) return;
    int p  = nodePtr[v];
    int pe = nodePtr[v + 1];
    float a0[8], a1[8];
#pragma unroll
    for (int k = 0; k < 8; ++k) { a0[k] = 0.f; a1[k] = 0.f; }
    int e = p + par;
    for (; e + 2 < pe; e += 4) {        // 2 edges in flight per lane
        int r0 = srt[e];
        int r1 = srt[e + 2];
        float4 p0 = *reinterpret_cast<const float4*>(h2h + (size_t)r0 * C2);
        float4 p1 = *reinterpret_cast<const float4*>(h2h + (size_t)r1 * C2);
        const __half2* h0 = reinterpret_cast<const __half2*>(&p0);
        const __half2* h1_ = reinterpret_cast<const __half2*>(&p1);
#pragma unroll
        for (int k = 0; k < 4; ++k) {
            float2 f0 = __half22float2(h0[k]);
            float2 f1 = __half22float2(h1_[k]);
            a0[2 * k] += f0.x; a0[2 * k + 1] += f0.y;
            a1[2 * k] += f1.x; a1[2 * k + 1] += f1.y;
        }
    }
    for (; e < pe; e += 2) {
        int r0 = srt[e];
        float4 p0 = *reinterpret_cast<const float4*>(h2h + (size_t)r0 * C2);
        const __half2* h0 = reinterpret_cast<const __half2*>(&p0);
#pragma unroll
        for (int k = 0; k < 4; ++k) {
            float2 f0 = __half22float2(h0[k]);
            a0[2 * k] += f0.x; a0[2 * k + 1] += f0.y;
        }
    }
#pragma unroll
    for (int k = 0; k < 8; ++k) a0[k] += a1[k];
    // merge parity partner (lane ^ 1)
#pragma unroll
    for (int k = 0; k < 8; ++k) a0[k] += __shfl_xor(a0[k], 1);
    if (par) return;

    float4 ps = *reinterpret_cast<const float4*>(h2h + (size_t)v * C2);
    const __half2* hs = reinterpret_cast<const __half2*>(&ps);
    float di = dinv[v];
    float z[C2];
#pragma unroll
    for (int k = 0; k < 4; ++k) {
        float2 fs = __half22float2(hs[k]);
        z[2 * k]     = di * (a0[2 * k] + fs.x) + b2[2 * k];
        z[2 * k + 1] = di * (a0[2 * k + 1] + fs.y) + b2[2 * k + 1];
    }
    float m = z[0];
#pragma unroll
    for (int j = 1; j < C2; ++j) m = fmaxf(m, z[j]);
    float s = 0.0f;
#pragma unroll
    for (int j = 0; j < C2; ++j) s += __expf(z[j] - m);
    float lse = m + logf(s);
    float4* o = reinterpret_cast<float4*>(out + (size_t)v * C2);
    o[0] = make_float4(z[0] - lse, z[1] - lse, z[2] - lse, z[3] - lse);
    o[1] = make_float4(z[4] - lse, z[5] - lse, z[6] - lse, z[7] - lse);
}

extern "C" void kernel_launch(void* const* d_in, const int* in_sizes, int n_in,
                              void* d_out, int out_size, void* d_ws, size_t ws_size,
                              hipStream_t stream) {
    const float* x  = (const float*)d_in[0];
    const int*   ei = (const int*)d_in[1];
    const float* W1 = (const float*)d_in[2];
    const float* b1 = (const float*)d_in[3];
    const float* W2 = (const float*)d_in[4];
    const float* b2 = (const float*)d_in[5];
    float* out = (float*)d_out;

    const int N = in_sizes[0] / F_IN;
    const int E = in_sizes[1] / 2;
    const int nbuck = (N + BNODES - 1) >> BSHIFT;        // 782
    const int M = NBLK * nbuck;                          // 256*782 (block-major)
    int chunk = (E + NBLK - 1) / NBLK;
    chunk = (chunk + 3) & ~3;                            // keep windows 16B-aligned

    // workspace layout (4B units); nodePtr padded to N+8 to keep h1h 16B-aligned
    int*    stage   = (int*)d_ws;                        // E
    int*    srt     = stage + E;                         // E
    int*    bbcScan = srt + E;                           // M
    int*    nodePtr = bbcScan + M;                       // N+8 (N+1 used)
    float*  dinv    = (float*)(nodePtr + N + 8);         // N
    __half* h1h     = (__half*)(dinv + N);               // 16N halves
    __half* h2h     = h1h + (size_t)16 * N;              // 8N halves

    const int TB = 256;

    binScatter2_kernel<<<NBLK, BIN_TB, 0, stream>>>(ei, E, chunk, nbuck, bbcScan, stage);
    sortCSR_kernel<<<nbuck, NBLK, 0, stream>>>(stage, bbcScan, E, nbuck, chunk, srt, nodePtr, dinv, N);
    gemm1_kernel<<<(N + TB - 1) / TB, TB, 0, stream>>>(x, W1, dinv, h1h, N);
    agg1_kernel<<<nbuck, AGG1_TB, 0, stream>>>(srt, nodePtr, h1h, dinv, b1, W2, h2h, N);
    agg2_kernel<<<(N + (AGG2_TB / 2) - 1) / (AGG2_TB / 2), AGG2_TB, 0, stream>>>(srt, nodePtr, h2h, dinv, b2, out, N);
}

// Round 21
// 112.375 us; speedup vs baseline: 1.2338x; 1.0088x over previous
//
#include <hip/hip_runtime.h>
#include <hip/hip_fp16.h>

#define F_IN 128
#define H1   16
#define C2   8
#define BSHIFT 7
#define BNODES 128            // nodes per bucket
#define MAXBUCK 1024          // LDS array bound (runtime nbuck=782)
#define NBLK 256              // binning windows (== threads in sortCSR)
#define BIN_TB 1024           // binScatter2 threads
#define CAP  6144             // sortCSR LDS record staging (avg bucket = 4096)
#define CHUNK_CAP 12800       // binScatter2 per-block edge capacity (chunk = 12500)
#define SRCMASK 0x1FFFF       // 17-bit source id (N < 131072)

// ---------- merged binning: LDS-staged sort + COALESCED int4 dump ----------
__global__ __launch_bounds__(BIN_TB) void binScatter2_kernel(
        const int* __restrict__ ei, int E, int chunk, int nbuck,
        int* __restrict__ bbcScan, int* __restrict__ stage) {
    __shared__ int h[MAXBUCK];            // 4 KB   histogram -> cursors
    __shared__ int sc[512];               // 2 KB   scan buffer
    __shared__ int ldsStage[CHUNK_CAP];   // 51.2 KB block-local sorted records
    int t = threadIdx.x;
    int blk = blockIdx.x;
    int base = blk * chunk;
    int csize = max(0, min(chunk, E - base));
    int blkBase = base;

    for (int i = t; i < MAXBUCK; i += BIN_TB) h[i] = 0;
    __syncthreads();

    const int* colp = ei + E + base;
    const int* rowp = ei + base;
    bool al4 = ((E & 3) == 0) && ((base & 3) == 0) && ((csize & 3) == 0);
    bool fit = (csize <= CHUNK_CAP);

    // pass 1: histogram of destination buckets
    if (al4) {
        const int4* cv = reinterpret_cast<const int4*>(colp);
        int nv = csize >> 2;
        for (int i = t; i < nv; i += BIN_TB) {
            int4 c4 = cv[i];
            atomicAdd(&h[c4.x >> BSHIFT], 1);
            atomicAdd(&h[c4.y >> BSHIFT], 1);
            atomicAdd(&h[c4.z >> BSHIFT], 1);
            atomicAdd(&h[c4.w >> BSHIFT], 1);
        }
    } else {
        for (int i = t; i < csize; i += BIN_TB) atomicAdd(&h[colp[i] >> BSHIFT], 1);
    }
    __syncthreads();

    // in-block exclusive scan of h[0..1024); threads t<512 own entries 2t, 2t+1
    int e0 = 0, e1 = 0, psum = 0;
    if (t < 512) {
        e0 = h[2 * t]; e1 = h[2 * t + 1];
        psum = e0 + e1;
        sc[t] = psum;
    }
    __syncthreads();
    for (int off = 1; off < 512; off <<= 1) {
        int tmp = (t < 512 && t >= off) ? sc[t - off] : 0;
        __syncthreads();
        if (t < 512) sc[t] += tmp;
        __syncthreads();
    }
    if (t < 512) {
        int excl = sc[t] - psum;
        if (fit) {
            h[2 * t] = excl;                 // LOCAL cursors for LDS staging
            h[2 * t + 1] = excl + e0;
        } else {
            h[2 * t] = blkBase + excl;       // global cursors (fallback)
            h[2 * t + 1] = blkBase + excl + e0;
        }
    }
    __syncthreads();

    // publish run starts for sortCSR: bbcScan = blkBase + excl
    for (int b = t; b < nbuck; b += BIN_TB)
        bbcScan[blk * nbuck + b] = blkBase + (fit ? h[b] : (h[b] - blkBase));
    __syncthreads();

    // pass 2: cursor-atomic positioned writes
    if (fit) {
        if (al4) {
            const int4* cv = reinterpret_cast<const int4*>(colp);
            const int4* rv = reinterpret_cast<const int4*>(rowp);
            int nv = csize >> 2;
            for (int i = t; i < nv; i += BIN_TB) {
                int4 c4 = cv[i];
                int4 r4 = rv[i];
                int p0 = atomicAdd(&h[c4.x >> BSHIFT], 1);
                ldsStage[p0] = (r4.x << BSHIFT) | (c4.x & (BNODES - 1));
                int p1 = atomicAdd(&h[c4.y >> BSHIFT], 1);
                ldsStage[p1] = (r4.y << BSHIFT) | (c4.y & (BNODES - 1));
                int p2 = atomicAdd(&h[c4.z >> BSHIFT], 1);
                ldsStage[p2] = (r4.z << BSHIFT) | (c4.z & (BNODES - 1));
                int p3 = atomicAdd(&h[c4.w >> BSHIFT], 1);
                ldsStage[p3] = (r4.w << BSHIFT) | (c4.w & (BNODES - 1));
            }
        } else {
            for (int i = t; i < csize; i += BIN_TB) {
                int r = rowp[i];
                int c = colp[i];
                int p = atomicAdd(&h[c >> BSHIFT], 1);
                ldsStage[p] = (r << BSHIFT) | (c & (BNODES - 1));
            }
        }
        __syncthreads();
        // coalesced int4 dump (base is x4-aligned -> 16B aligned)
        if (al4) {
            int4* gdst = reinterpret_cast<int4*>(stage + base);
            const int4* lsrc = reinterpret_cast<const int4*>(ldsStage);
            int nv = csize >> 2;
            for (int i = t; i < nv; i += BIN_TB)
                gdst[i] = lsrc[i];
        } else {
            for (int i = t; i < csize; i += BIN_TB)
                stage[base + i] = ldsStage[i];
        }
    } else {
        if (al4) {
            const int4* cv = reinterpret_cast<const int4*>(colp);
            const int4* rv = reinterpret_cast<const int4*>(rowp);
            int nv = csize >> 2;
            for (int i = t; i < nv; i += BIN_TB) {
                int4 c4 = cv[i];
                int4 r4 = rv[i];
                int p0 = atomicAdd(&h[c4.x >> BSHIFT], 1);
                stage[p0] = (r4.x << BSHIFT) | (c4.x & (BNODES - 1));
                int p1 = atomicAdd(&h[c4.y >> BSHIFT], 1);
                stage[p1] = (r4.y << BSHIFT) | (c4.y & (BNODES - 1));
                int p2 = atomicAdd(&h[c4.z >> BSHIFT], 1);
                stage[p2] = (r4.z << BSHIFT) | (c4.z & (BNODES - 1));
                int p3 = atomicAdd(&h[c4.w >> BSHIFT], 1);
                stage[p3] = (r4.w << BSHIFT) | (c4.w & (BNODES - 1));
            }
        } else {
            for (int i = t; i < csize; i += BIN_TB) {
                int r = rowp[i];
                int c = colp[i];
                int p = atomicAdd(&h[c >> BSHIFT], 1);
                stage[p] = (r << BSHIFT) | (c & (BNODES - 1));
            }
        }
    }
}

// ---------- within-bucket counting sort: int4-vectorized fused copy+count,
// rank packed in rec high byte, LDS positioned scatter + coalesced srt dump ----------
__global__ __launch_bounds__(NBLK) void sortCSR_kernel(
        const int* __restrict__ stage, const int* __restrict__ bbcScan,
        int E, int nbuck, int chunk, int* __restrict__ srt,
        int* __restrict__ nodePtr, float* __restrict__ dinv, int N) {
    __shared__ int ldsRec[CAP];       // 24.6 KB: rec | (rank<<24)
    __shared__ int ldsSorted[CAP];    // 24.6 KB: sorted source ids
    __shared__ int pref[NBLK];
    __shared__ int cnt[BNODES];
    __shared__ int cur[BNODES];
    int b = blockIdx.x;
    int t = threadIdx.x;

    int winS = min(t * chunk, E);
    int runS = min(bbcScan[t * nbuck + b], E);
    int runE = (b + 1 < nbuck) ? bbcScan[t * nbuck + b + 1] : min((t + 1) * chunk, E);
    runE = min(runE, E);
    int sz = runE - runS;

    // bucketStart = sum_t (runS - winS)
    pref[t] = runS - winS;
    __syncthreads();
    for (int off = NBLK / 2; off > 0; off >>= 1) {
        if (t < off) pref[t] += pref[t + off];
        __syncthreads();
    }
    int bucketStart = pref[0];
    __syncthreads();

    // inclusive scan of run sizes -> per-run LDS offset and total T
    pref[t] = sz;
    __syncthreads();
    for (int off = 1; off < NBLK; off <<= 1) {
        int tmp = (t >= off) ? pref[t - off] : 0;
        __syncthreads();
        pref[t] += tmp;
        __syncthreads();
    }
    int myOff = pref[t] - sz;
    int T = pref[NBLK - 1];

    if (t < BNODES) cnt[t] = 0;
    __syncthreads();

    bool fit = (T <= CAP);
    if (fit) {
        // fused copy + count, int4-vectorized (run is contiguous in stage)
        int i = 0;
        // lead-in to 16B alignment of (runS + i)
        while (i < sz && ((runS + i) & 3)) {
            int rec = stage[runS + i];
            int rank = atomicAdd(&cnt[rec & (BNODES - 1)], 1);
            ldsRec[myOff + i] = rec | (rank << 24);
            ++i;
        }
        for (; i + 3 < sz; i += 4) {
            int4 r4 = *reinterpret_cast<const int4*>(stage + runS + i);
            int k0 = atomicAdd(&cnt[r4.x & (BNODES - 1)], 1);
            ldsRec[myOff + i]     = r4.x | (k0 << 24);
            int k1 = atomicAdd(&cnt[r4.y & (BNODES - 1)], 1);
            ldsRec[myOff + i + 1] = r4.y | (k1 << 24);
            int k2 = atomicAdd(&cnt[r4.z & (BNODES - 1)], 1);
            ldsRec[myOff + i + 2] = r4.z | (k2 << 24);
            int k3 = atomicAdd(&cnt[r4.w & (BNODES - 1)], 1);
            ldsRec[myOff + i + 3] = r4.w | (k3 << 24);
        }
        for (; i < sz; ++i) {
            int rec = stage[runS + i];
            int rank = atomicAdd(&cnt[rec & (BNODES - 1)], 1);
            ldsRec[myOff + i] = rec | (rank << 24);
        }
    } else {
        for (int i = runS; i < runE; ++i)
            atomicAdd(&cnt[stage[i] & (BNODES - 1)], 1);
    }
    __syncthreads();

    // exclusive scan of cnt[128]
    if (t < BNODES) cur[t] = cnt[t];
    __syncthreads();
    for (int off = 1; off < BNODES; off <<= 1) {
        int tmp = 0;
        if (t < BNODES && t >= off) tmp = cur[t - off];
        __syncthreads();
        if (t < BNODES) cur[t] += tmp;
        __syncthreads();
    }
    if (t < BNODES) {
        int excl = cur[t] - cnt[t];
        int v = b * BNODES + t;
        if (v < N) {
            nodePtr[v] = bucketStart + excl;
            dinv[v] = rsqrtf((float)cnt[t] + 1.0f);
        }
        cur[t] = excl;                   // LOCAL base for LDS positioned writes
    }
    if (b == nbuck - 1 && t == 0) nodePtr[N] = E;
    __syncthreads();

    if (fit) {
        // positioned writes into LDS (cheap scatter), then coalesced dump
        for (int i = 0; i < sz; ++i) {
            int rec = ldsRec[myOff + i];
            int node = rec & (BNODES - 1);
            int rank = (int)((unsigned int)rec >> 24);
            ldsSorted[cur[node] + rank] = (rec >> BSHIFT) & SRCMASK;
        }
        __syncthreads();
        for (int i = t; i < T; i += NBLK)
            srt[bucketStart + i] = ldsSorted[i];
    } else {
        for (int i = runS; i < runE; ++i) {
            int rec = stage[i];
            int p = atomicAdd(&cur[rec & (BNODES - 1)], 1);
            srt[bucketStart + p] = rec >> BSHIFT;
        }
    }
}

// ---------- h1h = fp16( (x @ W1) * dinv[v] )  -- 3.2 MB, L2-resident ----------
__global__ void gemm1_kernel(const float* __restrict__ x, const float* __restrict__ W1,
                             const float* __restrict__ dinv, __half* __restrict__ h1h, int N) {
    __shared__ float sW[F_IN * H1];
    for (int i = threadIdx.x; i < F_IN * H1; i += blockDim.x) sW[i] = W1[i];
    __syncthreads();
    int v = blockIdx.x * blockDim.x + threadIdx.x;
    if (v >= N) return;
    float acc[H1];
#pragma unroll
    for (int j = 0; j < H1; ++j) acc[j] = 0.0f;
    const float4* xr = reinterpret_cast<const float4*>(x + (size_t)v * F_IN);
#pragma unroll 8
    for (int k4 = 0; k4 < F_IN / 4; ++k4) {
        float4 xv = xr[k4];
        const float* w = &sW[k4 * 4 * H1];
#pragma unroll
        for (int j = 0; j < H1; ++j) acc[j] += xv.x * w[j];
#pragma unroll
        for (int j = 0; j < H1; ++j) acc[j] += xv.y * w[H1 + j];
#pragma unroll
        for (int j = 0; j < H1; ++j) acc[j] += xv.z * w[2 * H1 + j];
#pragma unroll
        for (int j = 0; j < H1; ++j) acc[j] += xv.w * w[3 * H1 + j];
    }
    float di = dinv[v];
    alignas(16) __half2 hp[8];
#pragma unroll
    for (int q = 0; q < 8; ++q)
        hp[q] = __floats2half2_rn(acc[2 * q] * di, acc[2 * q + 1] * di);
    float4* ho = reinterpret_cast<float4*>(h1h + (size_t)v * H1);
    ho[0] = *reinterpret_cast<float4*>(&hp[0]);
    ho[1] = *reinterpret_cast<float4*>(&hp[4]);
}

// ---------- layer-1: 4 lanes/node, float4 (8-fp16) gathers + relu + GEMM2 fused ----------
#define AGG1_TB 512
__global__ __launch_bounds__(AGG1_TB) void agg1_kernel(
        const int* __restrict__ srt, const int* __restrict__ nodePtr,
        const __half* __restrict__ h1h, const float* __restrict__ dinv,
        const float* __restrict__ b1, const float* __restrict__ W2,
        __half* __restrict__ h2h, int N) {
    __shared__ float hrelu[BNODES][H1 + 1];
    __shared__ float sW[H1 * C2];
    __shared__ float sb[H1];
    for (int i = threadIdx.x; i < H1 * C2; i += AGG1_TB) sW[i] = W2[i];
    for (int i = threadIdx.x; i < H1; i += AGG1_TB) sb[i] = b1[i];
    __syncthreads();

    int base = blockIdx.x * BNODES;
    int vi = threadIdx.x >> 2;       // 128 groups = 128 nodes
    int ep = (threadIdx.x >> 1) & 1; // edge parity
    int q  = threadIdx.x & 1;        // row half (8 fp16 = 16 B)
    int v  = base + vi;

    if (v < N) {
        int p  = nodePtr[v];
        int pe = nodePtr[v + 1];
        float a0[8], a1[8];
#pragma unroll
        for (int k = 0; k < 8; ++k) { a0[k] = 0.f; a1[k] = 0.f; }
        int e = p + ep;
        for (; e + 2 < pe; e += 4) {
            int r0 = srt[e];
            int r1 = srt[e + 2];
            float4 p0 = *reinterpret_cast<const float4*>(h1h + (size_t)r0 * H1 + q * 8);
            float4 p1 = *reinterpret_cast<const float4*>(h1h + (size_t)r1 * H1 + q * 8);
            const __half2* h0 = reinterpret_cast<const __half2*>(&p0);
            const __half2* h1_ = reinterpret_cast<const __half2*>(&p1);
#pragma unroll
            for (int k = 0; k < 4; ++k) {
                float2 f0 = __half22float2(h0[k]);
                float2 f1 = __half22float2(h1_[k]);
                a0[2 * k] += f0.x; a0[2 * k + 1] += f0.y;
                a1[2 * k] += f1.x; a1[2 * k + 1] += f1.y;
            }
        }
        for (; e < pe; e += 2) {
            int r0 = srt[e];
            float4 p0 = *reinterpret_cast<const float4*>(h1h + (size_t)r0 * H1 + q * 8);
            const __half2* h0 = reinterpret_cast<const __half2*>(&p0);
#pragma unroll
            for (int k = 0; k < 4; ++k) {
                float2 f0 = __half22float2(h0[k]);
                a0[2 * k] += f0.x; a0[2 * k + 1] += f0.y;
            }
        }
#pragma unroll
        for (int k = 0; k < 8; ++k) a0[k] += a1[k];
#pragma unroll
        for (int k = 0; k < 8; ++k) a0[k] += __shfl_xor(a0[k], 2);

        if (ep == 0) {
            float4 ps = *reinterpret_cast<const float4*>(h1h + (size_t)v * H1 + q * 8);
            const __half2* hs = reinterpret_cast<const __half2*>(&ps);
            float di = dinv[v];
#pragma unroll
            for (int k = 0; k < 4; ++k) {
                float2 fs = __half22float2(hs[k]);
                int j0 = q * 8 + 2 * k, j1 = j0 + 1;
                hrelu[vi][j0] = fmaxf(di * (a0[2 * k] + fs.x) + sb[j0], 0.0f);
                hrelu[vi][j1] = fmaxf(di * (a0[2 * k + 1] + fs.y) + sb[j1], 0.0f);
            }
        }
    }
    __syncthreads();

    int j = threadIdx.x & 7;
    for (int vi2 = threadIdx.x >> 3; vi2 < BNODES; vi2 += (AGG1_TB >> 3)) {
        int v2 = base + vi2;
        if (v2 < N) {
            float dot = 0.0f;
#pragma unroll
            for (int k = 0; k < H1; ++k) dot += hrelu[vi2][k] * sW[k * C2 + j];
            h2h[(size_t)v2 * C2 + j] = __float2half(dot * dinv[v2]);
        }
    }
}

// ---------- layer-2: 2 lanes/node, float4 (8-fp16) gathers + log_softmax in-register ----------
#define AGG2_TB 256
__global__ __launch_bounds__(AGG2_TB) void agg2_kernel(
        const int* __restrict__ srt, const int* __restrict__ nodePtr,
        const __half* __restrict__ h2h, const float* __restrict__ dinv,
        const float* __restrict__ b2, float* __restrict__ out, int N) {
    int vi  = threadIdx.x >> 1;         // 128 nodes per block
    int par = threadIdx.x & 1;          // edge parity
    int v = blockIdx.x * (AGG2_TB / 2) + vi;
    if (v >= N) return;
    int p  = nodePtr[v];
    int pe = nodePtr[v + 1];
    float a0[8], a1[8];
#pragma unroll
    for (int k = 0; k < 8; ++k) { a0[k] = 0.f; a1[k] = 0.f; }
    int e = p + par;
    for (; e + 2 < pe; e += 4) {        // 2 edges in flight per lane
        int r0 = srt[e];
        int r1 = srt[e + 2];
        float4 p0 = *reinterpret_cast<const float4*>(h2h + (size_t)r0 * C2);
        float4 p1 = *reinterpret_cast<const float4*>(h2h + (size_t)r1 * C2);
        const __half2* h0 = reinterpret_cast<const __half2*>(&p0);
        const __half2* h1_ = reinterpret_cast<const __half2*>(&p1);
#pragma unroll
        for (int k = 0; k < 4; ++k) {
            float2 f0 = __half22float2(h0[k]);
            float2 f1 = __half22float2(h1_[k]);
            a0[2 * k] += f0.x; a0[2 * k + 1] += f0.y;
            a1[2 * k] += f1.x; a1[2 * k + 1] += f1.y;
        }
    }
    for (; e < pe; e += 2) {
        int r0 = srt[e];
        float4 p0 = *reinterpret_cast<const float4*>(h2h + (size_t)r0 * C2);
        const __half2* h0 = reinterpret_cast<const __half2*>(&p0);
#pragma unroll
        for (int k = 0; k < 4; ++k) {
            float2 f0 = __half22float2(h0[k]);
            a0[2 * k] += f0.x; a0[2 * k + 1] += f0.y;
        }
    }
#pragma unroll
    for (int k = 0; k < 8; ++k) a0[k] += a1[k];
    // merge parity partner (lane ^ 1)
#pragma unroll
    for (int k = 0; k < 8; ++k) a0[k] += __shfl_xor(a0[k], 1);
    if (par) return;

    float4 ps = *reinterpret_cast<const float4*>(h2h + (size_t)v * C2);
    const __half2* hs = reinterpret_cast<const __half2*>(&ps);
    float di = dinv[v];
    float z[C2];
#pragma unroll
    for (int k = 0; k < 4; ++k) {
        float2 fs = __half22float2(hs[k]);
        z[2 * k]     = di * (a0[2 * k] + fs.x) + b2[2 * k];
        z[2 * k + 1] = di * (a0[2 * k + 1] + fs.y) + b2[2 * k + 1];
    }
    float m = z[0];
#pragma unroll
    for (int j = 1; j < C2; ++j) m = fmaxf(m, z[j]);
    float s = 0.0f;
#pragma unroll
    for (int j = 0; j < C2; ++j) s += __expf(z[j] - m);
    float lse = m + logf(s);
    float4* o = reinterpret_cast<float4*>(out + (size_t)v * C2);
    o[0] = make_float4(z[0] - lse, z[1] - lse, z[2] - lse, z[3] - lse);
    o[1] = make_float4(z[4] - lse, z[5] - lse, z[6] - lse, z[7] - lse);
}

extern "C" void kernel_launch(void* const* d_in, const int* in_sizes, int n_in,
                              void* d_out, int out_size, void* d_ws, size_t ws_size,
                              hipStream_t stream) {
    const float* x  = (const float*)d_in[0];
    const int*   ei = (const int*)d_in[1];
    const float* W1 = (const float*)d_in[2];
    const float* b1 = (const float*)d_in[3];
    const float* W2 = (const float*)d_in[4];
    const float* b2 = (const float*)d_in[5];
    float* out = (float*)d_out;

    const int N = in_sizes[0] / F_IN;
    const int E = in_sizes[1] / 2;
    const int nbuck = (N + BNODES - 1) >> BSHIFT;        // 782
    const int M = NBLK * nbuck;                          // 256*782 (block-major)
    int chunk = (E + NBLK - 1) / NBLK;
    chunk = (chunk + 3) & ~3;                            // keep windows 16B-aligned

    // workspace layout (4B units); nodePtr padded to N+8 to keep h1h 16B-aligned
    int*    stage   = (int*)d_ws;                        // E
    int*    srt     = stage + E;                         // E
    int*    bbcScan = srt + E;                           // M
    int*    nodePtr = bbcScan + M;                       // N+8 (N+1 used)
    float*  dinv    = (float*)(nodePtr + N + 8);         // N
    __half* h1h     = (__half*)(dinv + N);               // 16N halves
    __half* h2h     = h1h + (size_t)16 * N;              // 8N halves

    const int TB = 256;

    binScatter2_kernel<<<NBLK, BIN_TB, 0, stream>>>(ei, E, chunk, nbuck, bbcScan, stage);
    sortCSR_kernel<<<nbuck, NBLK, 0, stream>>>(stage, bbcScan, E, nbuck, chunk, srt, nodePtr, dinv, N);
    gemm1_kernel<<<(N + TB - 1) / TB, TB, 0, stream>>>(x, W1, dinv, h1h, N);
    agg1_kernel<<<nbuck, AGG1_TB, 0, stream>>>(srt, nodePtr, h1h, dinv, b1, W2, h2h, N);
    agg2_kernel<<<(N + (AGG2_TB / 2) - 1) / (AGG2_TB / 2), AGG2_TB, 0, stream>>>(srt, nodePtr, h2h, dinv, b2, out, N);
}